// Round 6
// baseline (259.442 us; speedup 1.0000x reference)
//
#include <hip/hip_runtime.h>

typedef unsigned short u16;
typedef __bf16 bf16x8 __attribute__((ext_vector_type(8)));
typedef unsigned short u16x8 __attribute__((ext_vector_type(8)));
typedef float f32x4 __attribute__((ext_vector_type(4)));

// XOR swizzle key for [row][64] bf16 LDS tiles, 8-elem (16B) chunk granularity.
// Involution; spreads the 8 chunk-columns across banks per 8-row stripe.
#define KEY(r) ((((r) ^ ((r) >> 3)) & 7) << 3)

static __device__ __forceinline__ u16 f2b(float f) {
  union { float f; unsigned u; } x; x.f = f;
  unsigned r = x.u + 0x7FFFu + ((x.u >> 16) & 1u);  // RNE
  return (u16)(r >> 16);
}

static __device__ __forceinline__ bf16x8 ld_frag(const u16* p) {
  union { u16x8 s; bf16x8 b; } u;
  u.s = *reinterpret_cast<const u16x8*>(p);
  return u.b;
}

// ---------------- f32 -> bf16 convert (vectorized x4) ----------------
__global__ __launch_bounds__(256) void cvt_f32_bf16(const float* __restrict__ in,
                                                    u16* __restrict__ out, int n4) {
  int i = blockIdx.x * 256 + threadIdx.x;
  if (i >= n4) return;
  float4 v = reinterpret_cast<const float4*>(in)[i];
  ushort4 o;
  o.x = f2b(v.x); o.y = f2b(v.y); o.z = f2b(v.z); o.w = f2b(v.w);
  reinterpret_cast<ushort4*>(out)[i] = o;
}

// ---------------- GEMM body: 128x128 tile, BK=64 (m97 structure) ------------
// 4 waves 2x2, each wave 64x64 via 4x4 16x16x32 frags. global_load_lds w16,
// pre-swizzled source + swizzled ds_read (both-sides rule #21).
template <bool OUT_BF16>
static __device__ __forceinline__ void gemm_body(
    const u16* __restrict__ A, const u16* __restrict__ Bt,
    const float* __restrict__ bias, void* __restrict__ outp,
    int N, int K, int row0, int col0, float scale) {
  __shared__ alignas(16) u16 As[128 * 64];
  __shared__ alignas(16) u16 Bs[128 * 64];
  const int tid = threadIdx.x, wid = tid >> 6, lane = tid & 63;
  const int wr = wid >> 1, wc = wid & 1;
  const int lr = lane >> 3;         // 0..7
  const int lc = (lane & 7) * 8;    // 0..56
  const int frow = lane & 15, fk = (lane >> 4) * 8;
  f32x4 acc[4][4] = {};

  for (int k0 = 0; k0 < K; k0 += 64) {
    __syncthreads();
#pragma unroll
    for (int t = 0; t < 4; ++t) {
      const int r = wid * 32 + t * 8 + lr;
      __builtin_amdgcn_global_load_lds(
          (const __attribute__((address_space(1))) unsigned int*)(
              A + (size_t)(row0 + r) * K + k0 + (lc ^ KEY(r))),
          (__attribute__((address_space(3))) unsigned int*)(As + (wid * 32 + t * 8) * 64),
          16, 0, 0);
    }
#pragma unroll
    for (int t = 0; t < 4; ++t) {
      const int r = wid * 32 + t * 8 + lr;
      __builtin_amdgcn_global_load_lds(
          (const __attribute__((address_space(1))) unsigned int*)(
              Bt + (size_t)(col0 + r) * K + k0 + (lc ^ KEY(r))),
          (__attribute__((address_space(3))) unsigned int*)(Bs + (wid * 32 + t * 8) * 64),
          16, 0, 0);
    }
    __syncthreads();
#pragma unroll
    for (int ks = 0; ks < 2; ++ks) {
      bf16x8 a[4], b[4];
#pragma unroll
      for (int m = 0; m < 4; ++m) {
        const int r = wr * 64 + m * 16 + frow;
        a[m] = ld_frag(&As[r * 64 + ((ks * 32 + fk) ^ KEY(r))]);
      }
#pragma unroll
      for (int n = 0; n < 4; ++n) {
        const int r = wc * 64 + n * 16 + frow;
        b[n] = ld_frag(&Bs[r * 64 + ((ks * 32 + fk) ^ KEY(r))]);
      }
#pragma unroll
      for (int m = 0; m < 4; ++m)
#pragma unroll
        for (int n = 0; n < 4; ++n)
          acc[m][n] = __builtin_amdgcn_mfma_f32_16x16x32_bf16(a[m], b[n], acc[m][n], 0, 0, 0);
    }
  }
  const int colL = lane & 15, rb = (lane >> 4) * 4;
#pragma unroll
  for (int n = 0; n < 4; ++n) {
    const int gc = col0 + wc * 64 + n * 16 + colL;
    const float bv = bias[gc];
#pragma unroll
    for (int m = 0; m < 4; ++m)
#pragma unroll
      for (int r = 0; r < 4; ++r) {
        const int gr = row0 + wr * 64 + m * 16 + rb + r;
        const float v = (acc[m][n][r] + bv) * scale;
        if constexpr (OUT_BF16)
          reinterpret_cast<u16*>(outp)[(size_t)gr * N + gc] = f2b(v);
        else
          reinterpret_cast<float*>(outp)[(size_t)gr * N + gc] = v;
      }
  }
}

// Fused Q + KV projection (shared A panel; branch is block-uniform).
__global__ __launch_bounds__(256) void gemm_qkv(
    const u16* __restrict__ xb, const u16* __restrict__ wqb,
    const u16* __restrict__ wkvb, const float* __restrict__ bq,
    const float* __restrict__ bkv, u16* __restrict__ qb, u16* __restrict__ kvb) {
  const int row0 = blockIdx.x * 128;
  const int by = blockIdx.y;
  const u16* Bt; const float* bias; u16* out; int N, col0; float scale;
  if (by < 8) { Bt = wqb;  bias = bq;  out = qb;  N = 1024; col0 = by * 128;      scale = 0.125f; }
  else        { Bt = wkvb; bias = bkv; out = kvb; N = 2048; col0 = (by - 8) * 128; scale = 1.0f; }
  gemm_body<true>(xb, Bt, bias, out, N, 1024, row0, col0, scale);
}

__global__ __launch_bounds__(256) void gemm_o(
    const u16* __restrict__ yb, const u16* __restrict__ wob,
    const float* __restrict__ bo, float* __restrict__ out) {
  gemm_body<false>(yb, wob, bo, out, 1024, 1024, blockIdx.x * 128, blockIdx.y * 128, 1.0f);
}

// ---------------- Flash attention with ALiBi + causal ----------------
// grid: (B*H, T/32), qt = gridDim.y-1-blockIdx.y (LPT). block: 128 (2 waves),
// wave w owns q rows [qBase+16w, +16). K/V reg-prefetched (T14); all LDS
// tiles pitch-64 XOR-swizzled (conflict-free b128 frag reads).
__global__ __launch_bounds__(128) void attn_kernel(
    const u16* __restrict__ qb,   // [B*T,1024] bf16, pre-scaled by 1/8
    const u16* __restrict__ kvb,  // [B*T,2048] bf16 (k: h*64, v: 1024+h*64)
    u16* __restrict__ yb,         // [B*T,1024] bf16
    int T) {
  const int C = 1024;
  const int bh = blockIdx.x;
  const int qt = gridDim.y - 1 - blockIdx.y;
  const int b = bh >> 4, h = bh & 15;
  const float slope = (float)(h + 1) * 0.0625f;
  const int tid = threadIdx.x, wid = tid >> 6, lane = tid & 63;
  const int qBase = qt * 32;

  __shared__ alignas(16) u16 Ks[64 * 64];      // K[k][d ^ KEY(k)]
  __shared__ alignas(16) u16 Vt[64 * 64];      // V^T: Vt[d][k ^ KEY(d)]
  __shared__ alignas(16) u16 Ps[2][16 * 64];   // P[q][c ^ PK(q)] per wave

  const int frow = lane & 15, fk = (lane >> 4) * 8;
  const int col = lane & 15, rb = (lane >> 4) * 4;
  const int pk = ((lane >> 4) & 3) << 3;       // == PK(rb+r) for r<4

  // Q fragments (loop-invariant)
  const int q_row = qBase + wid * 16 + frow;
  const u16* qp = qb + (size_t)(b * T + q_row) * C + h * 64;
  const bf16x8 aq0 = ld_frag(qp + fk);
  const bf16x8 aq1 = ld_frag(qp + 32 + fk);

  float mrow[4] = {-1e30f, -1e30f, -1e30f, -1e30f};
  float lrow[4] = {0.f, 0.f, 0.f, 0.f};
  f32x4 accO[4] = {};

  const int st_r = tid >> 3;        // 0..15
  const int st_c = (tid & 7) * 8;   // 0..56
  const int vkj = tid & 7;          // st_c>>3

  const int nt = (qBase + 31) / 64 + 1;

  int4 kreg[4], vreg[4];
#pragma unroll
  for (int t = 0; t < 4; ++t) {  // prologue: tile 0
    const int r = st_r + 16 * t;
    const size_t g = (size_t)(b * T + r) * 2048 + h * 64 + st_c;
    kreg[t] = *reinterpret_cast<const int4*>(&kvb[g]);
    vreg[t] = *reinterpret_cast<const int4*>(&kvb[g + 1024]);
  }

  for (int kt = 0; kt < nt; ++kt) {
    const int kBase = kt * 64;
    // staged regs -> LDS (K rows, V transposed)
#pragma unroll
    for (int t = 0; t < 4; ++t) {
      const int r = st_r + 16 * t;
      *reinterpret_cast<int4*>(&Ks[r * 64 + (st_c ^ KEY(r))]) = kreg[t];
      const u16* pv = reinterpret_cast<const u16*>(&vreg[t]);
#pragma unroll
      for (int j = 0; j < 8; ++j) {
        const int d = st_c + j;
        Vt[d * 64 + (r ^ ((((j) ^ vkj) & 7) << 3))] = pv[j];  // == r ^ KEY(d)
      }
    }
    __syncthreads();
    // prefetch next tile into regs (latency hides under compute)
    if (kt + 1 < nt) {
#pragma unroll
      for (int t = 0; t < 4; ++t) {
        const int r = st_r + 16 * t;
        const size_t g = (size_t)(b * T + kBase + 64 + r) * 2048 + h * 64 + st_c;
        kreg[t] = *reinterpret_cast<const int4*>(&kvb[g]);
        vreg[t] = *reinterpret_cast<const int4*>(&kvb[g + 1024]);
      }
    }

    // S = Q K^T
    f32x4 accS[4] = {};
    __builtin_amdgcn_s_setprio(1);
#pragma unroll
    for (int n = 0; n < 4; ++n) {
      const int r = n * 16 + frow;
      bf16x8 bk0 = ld_frag(&Ks[r * 64 + (fk ^ KEY(r))]);
      accS[n] = __builtin_amdgcn_mfma_f32_16x16x32_bf16(aq0, bk0, accS[n], 0, 0, 0);
      bf16x8 bk1 = ld_frag(&Ks[r * 64 + ((32 + fk) ^ KEY(r))]);
      accS[n] = __builtin_amdgcn_mfma_f32_16x16x32_bf16(aq1, bk1, accS[n], 0, 0, 0);
    }
    __builtin_amdgcn_s_setprio(0);

    // online softmax; ALiBi bias = slope*kg (per-row -slope*qg shift cancels)
    float bn[4]; int kg[4];
#pragma unroll
    for (int n = 0; n < 4; ++n) { kg[n] = kBase + n * 16 + col; bn[n] = slope * (float)kg[n]; }
#pragma unroll
    for (int r = 0; r < 4; ++r) {
      const int qg = qBase + wid * 16 + rb + r;
      float s[4];
      float tmax = -1e30f;
#pragma unroll
      for (int n = 0; n < 4; ++n) {
        float v = accS[n][r] + bn[n];
        if (kg[n] > qg) v = -1e30f;
        s[n] = v;
        tmax = fmaxf(tmax, v);
      }
      tmax = fmaxf(tmax, __shfl_xor(tmax, 1));
      tmax = fmaxf(tmax, __shfl_xor(tmax, 2));
      tmax = fmaxf(tmax, __shfl_xor(tmax, 4));
      tmax = fmaxf(tmax, __shfl_xor(tmax, 8));
      const float newm = fmaxf(mrow[r], tmax);
      const float corr = __expf(mrow[r] - newm);
      mrow[r] = newm;
      float psum = 0.f;
#pragma unroll
      for (int n = 0; n < 4; ++n) {
        const float p = __expf(s[n] - newm);
        psum += p;
        Ps[wid][(rb + r) * 64 + ((n * 16 + col) ^ pk)] = f2b(p);
      }
      psum += __shfl_xor(psum, 1);
      psum += __shfl_xor(psum, 2);
      psum += __shfl_xor(psum, 4);
      psum += __shfl_xor(psum, 8);
      lrow[r] = lrow[r] * corr + psum;
#pragma unroll
      for (int n = 0; n < 4; ++n) accO[n][r] *= corr;
    }
    // no barrier: Ps is wave-private; within-wave ds ordering suffices

    // O += P @ V
    __builtin_amdgcn_s_setprio(1);
#pragma unroll
    for (int ks = 0; ks < 2; ++ks) {
      const int pkr = ((frow >> 2) & 3) << 3;  // PK(frow)
      bf16x8 ap = ld_frag(&Ps[wid][frow * 64 + ((ks * 32 + fk) ^ pkr)]);
#pragma unroll
      for (int n = 0; n < 4; ++n) {
        const int d = n * 16 + frow;
        bf16x8 bv = ld_frag(&Vt[d * 64 + ((ks * 32 + fk) ^ KEY(d))]);
        accO[n] = __builtin_amdgcn_mfma_f32_16x16x32_bf16(ap, bv, accO[n], 0, 0, 0);
      }
    }
    __builtin_amdgcn_s_setprio(0);
    __syncthreads();  // all reads done before next tile's LDS writes
  }

  // normalize + store
#pragma unroll
  for (int r = 0; r < 4; ++r) {
    const float inv = 1.0f / lrow[r];
    const int qg = qBase + wid * 16 + rb + r;
    u16* yrow = yb + (size_t)(b * T + qg) * C + h * 64;
#pragma unroll
    for (int n = 0; n < 4; ++n) yrow[n * 16 + col] = f2b(accO[n][r] * inv);
  }
}

extern "C" void kernel_launch(void* const* d_in, const int* in_sizes, int n_in,
                              void* d_out, int out_size, void* d_ws, size_t ws_size,
                              hipStream_t stream) {
  const float* x   = (const float*)d_in[0];
  // d_in[1] = freqs_cis (unused under ALiBi)
  const float* Wq  = (const float*)d_in[2];
  const float* bq  = (const float*)d_in[3];
  const float* Wkv = (const float*)d_in[4];
  const float* bkv = (const float*)d_in[5];
  const float* Wo  = (const float*)d_in[6];
  const float* bo  = (const float*)d_in[7];
  float* out = (float*)d_out;

  const int B = 2, T = 2048, C = 1024;
  const int M = B * T;  // 4096

  char* ws = (char*)d_ws;
  u16* xb   = (u16*)(ws + 0);          // 4096x1024  (8 MiB)
  u16* wqb  = (u16*)(ws + 8388608);    // 1024x1024  (2 MiB)
  u16* wkvb = (u16*)(ws + 10485760);   // 2048x1024  (4 MiB)
  u16* wob  = (u16*)(ws + 14680064);   // 1024x1024  (2 MiB)
  u16* qb   = (u16*)(ws + 16777216);   // 4096x1024  (8 MiB)
  u16* kvb  = (u16*)(ws + 25165824);   // 4096x2048  (16 MiB)
  u16* yb   = (u16*)(ws + 41943040);   // 4096x1024  (8 MiB)

  cvt_f32_bf16<<<(M * C / 4 + 255) / 256, 256, 0, stream>>>(x, xb, M * C / 4);
  cvt_f32_bf16<<<(C * C / 4 + 255) / 256, 256, 0, stream>>>(Wq, wqb, C * C / 4);
  cvt_f32_bf16<<<(2 * C * C / 4 + 255) / 256, 256, 0, stream>>>(Wkv, wkvb, 2 * C * C / 4);
  cvt_f32_bf16<<<(C * C / 4 + 255) / 256, 256, 0, stream>>>(Wo, wob, C * C / 4);

  // fused: q = (x@Wq^T + bq)*0.125 ; kv = x@Wkv^T + bkv
  gemm_qkv<<<dim3(M / 128, 8 + 16), 256, 0, stream>>>(xb, wqb, wkvb, bq, bkv, qb, kvb);
  // flash attention (grid: bh x qtile32, reversed for LPT balance)
  attn_kernel<<<dim3(B * 16, T / 32), 128, 0, stream>>>(qb, kvb, yb, T);
  // out = y @ Wo^T + bo  (f32 out)
  gemm_o<<<dim3(M / 128, C / 128), 256, 0, stream>>>(yb, wob, bo, out);
}